// Round 12
// baseline (119.505 us; speedup 1.0000x reference)
//
#include <hip/hip_runtime.h>
#include <math.h>

#define MST   128
#define DOBS  8
#define TLEN  131072
#define LOG2PI_F 1.8378770664093453f

#define CLEN  4
#define NW    (TLEN / CLEN / 16)   /* 2048 waves: two per SIMD */
#define WARM  48
#define NSTEP (WARM + CLEN)        /* 52 */
#define GPAD  128
#define EROWS 16

typedef __attribute__((ext_vector_type(8))) short v8s;
typedef __attribute__((ext_vector_type(4))) float v4f;
typedef __attribute__((ext_vector_type(4))) unsigned int v4u;

__device__ __forceinline__ unsigned short f2bf_rne(float x) {
  unsigned int b = __builtin_bit_cast(unsigned int, x);
  unsigned int r = b + 0x7FFFu + ((b >> 16) & 1u);
  return (unsigned short)(r >> 16);
}
__device__ __forceinline__ unsigned cvtpk(float a, float b) {
  unsigned r;
  asm("v_cvt_pk_bf16_f32 %0, %1, %2" : "=v"(r) : "v"(a), "v"(b));
  return r;
}
__device__ __forceinline__ float bflo(unsigned u) {
  return __builtin_bit_cast(float, u << 16);
}
__device__ __forceinline__ float bfhi(unsigned u) {
  return __builtin_bit_cast(float, u & 0xFFFF0000u);
}

/* ---------- kernel 1: Gamma (f32, [src][dst]) + u0 + emission consts ---------- */
__global__ void build_params(const float* __restrict__ tl,
                             const float* __restrict__ il,
                             const float* __restrict__ ls,
                             float* __restrict__ Gf,
                             float* __restrict__ u0,
                             float* __restrict__ isb,
                             float* __restrict__ cstb) {
  __shared__ float red[MST];
  const int j = threadIdx.x;
  const int b = blockIdx.x;
  float lg;
  if (b < MST) lg = (j == b) ? 0.0f : tl[b * (MST - 1) + (j > b ? j - 1 : j)];
  else         lg = il[j];
  float e = __expf(lg);
  red[j] = e;
  __syncthreads();
  for (int s = MST / 2; s > 0; s >>= 1) {
    if (j < s) red[j] += red[j + s];
    __syncthreads();
  }
  float val = e / red[0];
  if (b < MST) {
    Gf[b * MST + j] = val;
  } else {
    u0[j] = val;
    float c = -((float)DOBS * 0.5f) * LOG2PI_F;
#pragma unroll
    for (int d = 0; d < DOBS; ++d) {
      float l = ls[j * DOBS + d];
      isb[j * DOBS + d] = __expf(-l);
      c -= l;
    }
    cstb[j] = c;
  }
}

/* ---------- kernel 1b: permuted Gamma^T A-fragments (bf16 RNE) ---------- */
__global__ void build_afrag(const float* __restrict__ Gf,
                            unsigned short* __restrict__ GA) {
  const int idx = blockIdx.x * 64 + threadIdx.x;  /* (m*4+kt)*64 + l */
  const int l  = idx & 63;
  const int mk = idx >> 6;
  const int kt = mk & 3, m = mk >> 2;
  const int i  = l & 15, hh = l >> 4;
  const int rg = 16 * m + i;
  const int lam = ((rg >> 5) << 5) | (((rg >> 2) & 3) << 3) | (((rg >> 4) & 1) << 2) | (rg & 3);
  unsigned short o[8];
#pragma unroll
  for (int j = 0; j < 8; ++j) {
    const int src = 32 * kt + 8 * hh + j;
    o[j] = f2bf_rne(Gf[src * MST + lam]);
  }
  *(v4u*)(GA + (size_t)idx * 8) = *(const v4u*)o;
}

/* ---------- kernel 2: emission densities -> bf16, XCD-aligned with consumer ---------- */
__global__ void emis_kernel(const float* __restrict__ y,
                            const float* __restrict__ mu,
                            const float* __restrict__ isb,
                            const float* __restrict__ cstb,
                            unsigned short* __restrict__ g0) {
  /* logical block: contiguous t-ranges stay on one XCD (matches scan swizzle) */
  const int lb = ((blockIdx.x & 7) << 10) | (blockIdx.x >> 3);
  const int j  = threadIdx.x;
  const int tb = lb * EROWS;
  __shared__ float ysh[EROWS * DOBS];
  ysh[j] = y[(unsigned)tb * DOBS + j];
  __syncthreads();
  float m[DOBS], is[DOBS];
  float cst = cstb[j];
#pragma unroll
  for (int d = 0; d < DOBS; ++d) { m[d] = mu[j * DOBS + d]; is[d] = isb[j * DOBS + d]; }
#pragma unroll
  for (int r = 0; r < EROWS; ++r) {
    float q = 0.0f;
#pragma unroll
    for (int d = 0; d < DOBS; ++d) {
      float z = (ysh[r * DOBS + d] - m[d]) * is[d];
      q = fmaf(z, z, q);
    }
    g0[(unsigned)(tb + r) * MST + j] = f2bf_rne(__expf(fmaf(-0.5f, q, cst)));
  }
}

/* ---------- scan internals ---------- */
__device__ __forceinline__ void packB(const v4f* w, v8s* Bh, v8s* Bl, bool full) {
#pragma unroll
  for (int kt = 0; kt < 4; ++kt) {
    const v4f wa = w[2 * kt], wb = w[2 * kt + 1];
    const unsigned r0 = cvtpk(wa[0], wa[1]), r1 = cvtpk(wa[2], wa[3]);
    const unsigned r2 = cvtpk(wb[0], wb[1]), r3 = cvtpk(wb[2], wb[3]);
    Bh[kt] = __builtin_bit_cast(v8s, (v4u){r0, r1, r2, r3});
    if (full) {
      const float l0 = wa[0] - bflo(r0);
      const float l1 = wa[1] - bfhi(r0);
      const float l2 = wa[2] - bflo(r1);
      const float l3 = wa[3] - bfhi(r1);
      const float l4 = wb[0] - bflo(r2);
      const float l5 = wb[1] - bfhi(r2);
      const float l6 = wb[2] - bflo(r3);
      const float l7 = wb[3] - bfhi(r3);
      Bl[kt] = __builtin_bit_cast(v8s, (v4u){cvtpk(l0, l1), cvtpk(l2, l3),
                                             cvtpk(l4, l5), cvtpk(l6, l7)});
    }
  }
}

/* one scan step: consumes `cur` (g[tcur] raw bf16) and refills it with g[tcur+3].
   MF: include state-lo MFMA pass; PF: produce full hi/lo pack.
   LP: live/inject checks possible (runtime, wave-uniform n). */
template<bool MF, bool PF, bool LP>
__device__ __forceinline__ void step(
    int n, int wid, int c, int h,
    const v8s* A, v8s* Bh, v8s* Bl, v4u (&cur)[4],
    float& inv, unsigned& gvo, unsigned& uvo,
    const char* gbase, const float* u0,
    char* outUt, char* outF, char* outUtt) {
  const bool live = LP && (n >= WARM);

  /* 1. D = W~ @ Gamma_hi (state hi, + state lo if MF) */
  v4f D[8] = {};
#pragma unroll
  for (int kt = 0; kt < 4; ++kt)
#pragma unroll
    for (int m = 0; m < 8; ++m)
      D[m] = __builtin_amdgcn_mfma_f32_16x16x32_bf16(A[m * 4 + kt], Bh[kt], D[m], 0, 0, 0);
  if (MF) {
#pragma unroll
    for (int kt = 0; kt < 4; ++kt)
#pragma unroll
      for (int m = 0; m < 8; ++m)
        D[m] = __builtin_amdgcn_mfma_f32_16x16x32_bf16(A[m * 4 + kt], Bl[kt], D[m], 0, 0, 0);
  }

  /* 2. convert g (bf16->f32) and fold inv_{n-1} */
  v4f gci[8];
#pragma unroll
  for (int mm = 0; mm < 4; ++mm) {
    const v4u raw = cur[mm];
    gci[2 * mm + 0] = (v4f){bflo(raw.x), bfhi(raw.x), bflo(raw.y), bfhi(raw.y)} * inv;
    gci[2 * mm + 1] = (v4f){bflo(raw.z), bfhi(raw.z), bflo(raw.w), bfhi(raw.w)} * inv;
  }

  /* 3. refill cur with g[tcur+3] (3-step latency slack; XCD-L2-local) */
#pragma unroll
  for (int mm = 0; mm < 4; ++mm)
    cur[mm] = *(const v4u*)(gbase + (gvo + (unsigned)mm * 64u));
  gvo += 256u;

  /* 4. predicted dist -> Utt (live, cached: L2 merges lane stores); w~ = p~ * g */
  if (live) {
#pragma unroll
    for (int m = 0; m < 8; ++m) {
      v4f p = D[m] * inv;
      *(v4f*)(outUtt + (uvo + (m >> 1) * 128 + (m & 1) * 16)) = p;
    }
  }
  v4f w[8];
#pragma unroll
  for (int m = 0; m < 8; ++m) w[m] = D[m] * gci[m];

  /* 5. exact u0 injection for wave-0 early chains (state at t=-1 := u0) */
  if (LP) {
    if (wid == 0 && n < WARM && ((n & 3) == 3)) {
      const int ctar = (WARM - 1 - n) >> 2;
#pragma unroll
      for (int m = 0; m < 8; ++m) {
        v4f uv = *(const v4f*)(u0 + (m >> 1) * 32 + h * 8 + (m & 1) * 4);
        if (c == ctar) w[m] = uv;
      }
    }
  }

  /* 6. rowsum S = f_t (off critical path: inv used only after next MFMAs) */
  v4f a0 = w[0] + w[1], a1 = w[2] + w[3], a2 = w[4] + w[5], a3 = w[6] + w[7];
  v4f a6 = (a0 + a1) + (a2 + a3);
  float s = (a6[0] + a6[1]) + (a6[2] + a6[3]);
  s += __shfl_xor(s, 16);
  s += __shfl_xor(s, 32);
  const float invn = __builtin_amdgcn_rcpf(s);

  /* 7. repack state (layout-closed: no cross-lane moves) */
  packB(w, Bh, Bl, PF);

  /* 8. filtered dist + f (live) */
  if (live) {
#pragma unroll
    for (int m = 0; m < 8; ++m) {
      v4f ut = w[m] * invn;
      *(v4f*)(outUt + (uvo + (m >> 1) * 128 + (m & 1) * 16)) = ut;
    }
    if (h == 0) *(float*)(outF + (uvo >> 7)) = s;
  }
  uvo += 512u;
  inv = invn;
}

/* ---------- kernel 3: barrier-free in-register MFMA scan, 2 waves/SIMD ---------- */
__global__ __launch_bounds__(64, 2)
void hmm_scan(const char* __restrict__ gbase,     /* bf16 rows: g[t] at (t+GPAD)*256 B */
              const unsigned short* __restrict__ GA,
              const float* __restrict__ u0,
              char* __restrict__ outUt,
              char* __restrict__ outF,
              char* __restrict__ outUtt) {
  const int l = threadIdx.x;
  const int h = l >> 4, c = l & 15;
  /* XCD swizzle: waves sharing a g-region land on one XCD (bid%8 = XCD slot) */
  const int wid = ((blockIdx.x & 7) << 8) | (blockIdx.x >> 3);
  const int t00 = (wid * 16 + c) * CLEN;
  const int t0  = t00 - WARM;

  /* Gamma^T A-fragments: 32 x v8s = 128 VGPR, loop-invariant */
  v8s A[32];
#pragma unroll
  for (int f = 0; f < 32; ++f)
    A[f] = *(const v8s*)(GA + (size_t)(f * 64 + l) * 8);

  /* initial state: uniform; wave-0 chain WARM/CLEN starts exactly at u0 */
  v4f w[8];
#pragma unroll
  for (int m = 0; m < 8; ++m)
    w[m] = (v4f){1.0f / MST, 1.0f / MST, 1.0f / MST, 1.0f / MST};
  if (wid == 0 && c == (WARM / CLEN)) {
#pragma unroll
    for (int m = 0; m < 8; ++m)
      w[m] = *(const v4f*)(u0 + (m >> 1) * 32 + h * 8 + (m & 1) * 4);
  }
  float inv = 1.0f;

  v8s Bh[4], Bl[4];
  packB(w, Bh, Bl, true);

  /* g pipeline: three raw bf16 row-buffers, refilled in place; buffer = n mod 3 */
  unsigned gvo = (unsigned)((t0 + GPAD) * 256 + h * 16);
  v4u gA[4], gB[4], gC[4];
#pragma unroll
  for (int mm = 0; mm < 4; ++mm) {
    gA[mm] = *(const v4u*)(gbase + (gvo + (unsigned)mm * 64u));
    gB[mm] = *(const v4u*)(gbase + (gvo + 256u + (unsigned)mm * 64u));
    gC[mm] = *(const v4u*)(gbase + (gvo + 512u + (unsigned)mm * 64u));
  }
  gvo += 768u;                                   /* -> t0+3 */
  unsigned uvo = (unsigned)(t0 * 512 + h * 32);

#define SARG wid, c, h, A, Bh, Bl
#define TAIL inv, gvo, uvo, gbase, u0, outUt, outF, outUtt
  /* phase A: hi-only state, rolled (13 iters x 3 steps), n = 0..38 */
#pragma clang loop unroll(disable)
  for (int n = 0; n < 39; n += 3) {
    step<false, false, true>(n + 0, SARG, gA, TAIL);
    step<false, false, true>(n + 1, SARG, gB, TAIL);
    step<false, false, true>(n + 2, SARG, gC, TAIL);
  }
  /* transition: hi-only MFMA, FULL pack */
  step<false, true, true>(39, SARG, gA, TAIL);
  /* phase B: full split, live when n>=WARM; rolled (4 iters x 3), n = 40..51 */
#pragma clang loop unroll(disable)
  for (int n = 40; n < 52; n += 3) {
    step<true, true, true>(n + 0, SARG, gB, TAIL);
    step<true, true, true>(n + 1, SARG, gC, TAIL);
    step<true, true, true>(n + 2, SARG, gA, TAIL);
  }
#undef SARG
#undef TAIL
}

extern "C" void kernel_launch(void* const* d_in, const int* in_sizes, int n_in,
                              void* d_out, int out_size, void* d_ws, size_t ws_size,
                              hipStream_t stream) {
  const float* y  = (const float*)d_in[0];
  const float* tl = (const float*)d_in[1];
  const float* il = (const float*)d_in[2];
  const float* mu = (const float*)d_in[3];
  const float* ls = (const float*)d_in[4];

  /* ws: bf16 g (padded) | u0 | Gf | GA | isb | cstb  (~34 MB) */
  unsigned short* gf16 = (unsigned short*)d_ws;         /* (GPAD+TLEN+GPAD) x 128 bf16 */
  unsigned short* g0   = gf16 + (size_t)GPAD * MST;
  float* u0 = (float*)(gf16 + (size_t)(TLEN + 2 * GPAD) * MST);
  float* Gf = u0 + MST;
  unsigned short* GA = (unsigned short*)(Gf + MST * MST);
  float* isb  = (float*)(GA + 32 * 64 * 8);
  float* cstb = isb + MST * DOBS;

  char* outUt  = (char*)d_out;
  char* outF   = outUt + (size_t)TLEN * MST * 4;
  char* outUtt = outF + (size_t)TLEN * 4;

  build_params<<<MST + 1, MST, 0, stream>>>(tl, il, ls, Gf, u0, isb, cstb);
  build_afrag<<<32, 64, 0, stream>>>(Gf, GA);
  emis_kernel<<<TLEN / EROWS, MST, 0, stream>>>(y, mu, isb, cstb, g0);
  hmm_scan<<<NW, 64, 0, stream>>>((const char*)gf16, GA, u0, outUt, outF, outUtt);
}

// Round 13
// 78.393 us; speedup vs baseline: 1.5244x; 1.5244x over previous
//
#include <hip/hip_runtime.h>
#include <math.h>

#define MST   128
#define DOBS  8
#define TLEN  131072
#define LOG2PI_F 1.8378770664093453f

#define CLEN  8
#define NW    (TLEN / CLEN / 16)   /* 1024 waves: one per SIMD */
#define WARM  32
#define NSTEP (WARM + CLEN)        /* 40 */
#define GPAD  128
#define EROWS 16

typedef __attribute__((ext_vector_type(8))) short v8s;
typedef __attribute__((ext_vector_type(4))) float v4f;
typedef __attribute__((ext_vector_type(4))) unsigned int v4u;

__device__ __forceinline__ unsigned short f2bf_rne(float x) {
  unsigned int b = __builtin_bit_cast(unsigned int, x);
  unsigned int r = b + 0x7FFFu + ((b >> 16) & 1u);
  return (unsigned short)(r >> 16);
}
__device__ __forceinline__ unsigned cvtpk(float a, float b) {
  unsigned r;
  asm("v_cvt_pk_bf16_f32 %0, %1, %2" : "=v"(r) : "v"(a), "v"(b));
  return r;
}
__device__ __forceinline__ float bflo(unsigned u) {
  return __builtin_bit_cast(float, u << 16);
}
__device__ __forceinline__ float bfhi(unsigned u) {
  return __builtin_bit_cast(float, u & 0xFFFF0000u);
}

/* ---------- kernel 1: Gamma (f32, [src][dst]) + u0 + emission consts ---------- */
__global__ void build_params(const float* __restrict__ tl,
                             const float* __restrict__ il,
                             const float* __restrict__ ls,
                             float* __restrict__ Gf,
                             float* __restrict__ u0,
                             float* __restrict__ isb,
                             float* __restrict__ cstb) {
  __shared__ float red[MST];
  const int j = threadIdx.x;
  const int b = blockIdx.x;
  float lg;
  if (b < MST) lg = (j == b) ? 0.0f : tl[b * (MST - 1) + (j > b ? j - 1 : j)];
  else         lg = il[j];
  float e = __expf(lg);
  red[j] = e;
  __syncthreads();
  for (int s = MST / 2; s > 0; s >>= 1) {
    if (j < s) red[j] += red[j + s];
    __syncthreads();
  }
  float val = e / red[0];
  if (b < MST) {
    Gf[b * MST + j] = val;
  } else {
    u0[j] = val;
    float c = -((float)DOBS * 0.5f) * LOG2PI_F;
#pragma unroll
    for (int d = 0; d < DOBS; ++d) {
      float l = ls[j * DOBS + d];
      isb[j * DOBS + d] = __expf(-l);
      c -= l;
    }
    cstb[j] = c;
  }
}

/* ---------- kernel 1b: permuted Gamma^T A-fragments (bf16 RNE) ---------- */
__global__ void build_afrag(const float* __restrict__ Gf,
                            unsigned short* __restrict__ GA) {
  const int idx = blockIdx.x * 64 + threadIdx.x;  /* (m*4+kt)*64 + l */
  const int l  = idx & 63;
  const int mk = idx >> 6;
  const int kt = mk & 3, m = mk >> 2;
  const int i  = l & 15, hh = l >> 4;
  const int rg = 16 * m + i;
  const int lam = ((rg >> 5) << 5) | (((rg >> 2) & 3) << 3) | (((rg >> 4) & 1) << 2) | (rg & 3);
  unsigned short o[8];
#pragma unroll
  for (int j = 0; j < 8; ++j) {
    const int src = 32 * kt + 8 * hh + j;
    o[j] = f2bf_rne(Gf[src * MST + lam]);
  }
  *(v4u*)(GA + (size_t)idx * 8) = *(const v4u*)o;
}

/* ---------- kernel 2: emission densities -> bf16, XCD-aligned with consumer ---------- */
__global__ void emis_kernel(const float* __restrict__ y,
                            const float* __restrict__ mu,
                            const float* __restrict__ isb,
                            const float* __restrict__ cstb,
                            unsigned short* __restrict__ g0) {
  /* logical block: contiguous t-ranges stay on one XCD (matches scan swizzle) */
  const int lb = ((blockIdx.x & 7) << 10) | (blockIdx.x >> 3);
  const int j  = threadIdx.x;
  const int tb = lb * EROWS;
  __shared__ float ysh[EROWS * DOBS];
  ysh[j] = y[(unsigned)tb * DOBS + j];
  __syncthreads();
  float m[DOBS], is[DOBS];
  float cst = cstb[j];
#pragma unroll
  for (int d = 0; d < DOBS; ++d) { m[d] = mu[j * DOBS + d]; is[d] = isb[j * DOBS + d]; }
#pragma unroll
  for (int r = 0; r < EROWS; ++r) {
    float q = 0.0f;
#pragma unroll
    for (int d = 0; d < DOBS; ++d) {
      float z = (ysh[r * DOBS + d] - m[d]) * is[d];
      q = fmaf(z, z, q);
    }
    g0[(unsigned)(tb + r) * MST + j] = f2bf_rne(__expf(fmaf(-0.5f, q, cst)));
  }
}

/* ---------- scan internals ---------- */
__device__ __forceinline__ void packBh(const v4f* w, v8s* Bh) {
#pragma unroll
  for (int kt = 0; kt < 4; ++kt) {
    const v4f wa = w[2 * kt], wb = w[2 * kt + 1];
    Bh[kt] = __builtin_bit_cast(v8s, (v4u){cvtpk(wa[0], wa[1]), cvtpk(wa[2], wa[3]),
                                           cvtpk(wb[0], wb[1]), cvtpk(wb[2], wb[3])});
  }
}

/* one scan step: consumes `cur` (g[tcur] raw bf16), refills it with g[tcur+3].
   Hi-only state (bf16 RNE); live = n >= WARM (wave-uniform runtime branch). */
__device__ __forceinline__ void step(
    int n, int wid, int c, int h,
    const v8s* A, v8s* Bh, v4u (&cur)[4],
    float& inv, unsigned& gvo, unsigned& uvo,
    const char* gbase, const float* u0,
    char* outUt, char* outF, char* outUtt) {
  const bool live = n >= WARM;

  /* 1. D = W~ @ Gamma (hi-only state) */
  v4f D[8] = {};
#pragma unroll
  for (int kt = 0; kt < 4; ++kt)
#pragma unroll
    for (int m = 0; m < 8; ++m)
      D[m] = __builtin_amdgcn_mfma_f32_16x16x32_bf16(A[m * 4 + kt], Bh[kt], D[m], 0, 0, 0);

  /* 2. convert g (bf16->f32), fold inv_{n-1} */
  v4f gci[8];
#pragma unroll
  for (int mm = 0; mm < 4; ++mm) {
    const v4u raw = cur[mm];
    gci[2 * mm + 0] = (v4f){bflo(raw.x), bfhi(raw.x), bflo(raw.y), bfhi(raw.y)} * inv;
    gci[2 * mm + 1] = (v4f){bflo(raw.z), bfhi(raw.z), bflo(raw.w), bfhi(raw.w)} * inv;
  }

  /* 3. refill cur with g[tcur+3] (3-step latency slack; XCD-L2-local) */
#pragma unroll
  for (int mm = 0; mm < 4; ++mm)
    cur[mm] = *(const v4u*)(gbase + (gvo + (unsigned)mm * 64u));
  gvo += 256u;

  /* 4. predicted dist -> Utt (live); w~ = p~ * g */
  if (live) {
#pragma unroll
    for (int m = 0; m < 8; ++m) {
      v4f p = D[m] * inv;
      *(v4f*)(outUtt + (uvo + (m >> 1) * 128 + (m & 1) * 16)) = p;
    }
  }
  v4f w[8];
#pragma unroll
  for (int m = 0; m < 8; ++m) w[m] = D[m] * gci[m];

  /* 5. exact u0 injection for wave-0 early chains (state at t=-1 := u0) */
  if (wid == 0 && n < WARM && ((n & 7) == 7)) {
    const int ctar = (WARM - 1 - n) >> 3;
#pragma unroll
    for (int m = 0; m < 8; ++m) {
      v4f uv = *(const v4f*)(u0 + (m >> 1) * 32 + h * 8 + (m & 1) * 4);
      if (c == ctar) w[m] = uv;
    }
  }

  /* 6. rowsum S = f_t */
  v4f a0 = w[0] + w[1], a1 = w[2] + w[3], a2 = w[4] + w[5], a3 = w[6] + w[7];
  v4f a6 = (a0 + a1) + (a2 + a3);
  float s = (a6[0] + a6[1]) + (a6[2] + a6[3]);
  s += __shfl_xor(s, 16);
  s += __shfl_xor(s, 32);
  const float invn = __builtin_amdgcn_rcpf(s);

  /* 7. repack state (hi-only, layout-closed) */
  packBh(w, Bh);

  /* 8. filtered dist + f (live) */
  if (live) {
#pragma unroll
    for (int m = 0; m < 8; ++m) {
      v4f ut = w[m] * invn;
      *(v4f*)(outUt + (uvo + (m >> 1) * 128 + (m & 1) * 16)) = ut;
    }
    if (h == 0) *(float*)(outF + (uvo >> 7)) = s;
  }
  uvo += 512u;
  inv = invn;
}

/* ---------- kernel 3: barrier-free in-register MFMA scan, hi-only state ---------- */
__global__ __launch_bounds__(64, 1)
void hmm_scan(const char* __restrict__ gbase,     /* bf16 rows: g[t] at (t+GPAD)*256 B */
              const unsigned short* __restrict__ GA,
              const float* __restrict__ u0,
              char* __restrict__ outUt,
              char* __restrict__ outF,
              char* __restrict__ outUtt) {
  const int l = threadIdx.x;
  const int h = l >> 4, c = l & 15;
  /* XCD swizzle: waves sharing a g-region land on one XCD */
  const int wid = ((blockIdx.x & 7) << 7) | (blockIdx.x >> 3);
  const int t00 = (wid * 16 + c) * CLEN;
  const int t0  = t00 - WARM;

  /* Gamma^T A-fragments: 32 x v8s = 128 VGPR, loop-invariant */
  v8s A[32];
#pragma unroll
  for (int f = 0; f < 32; ++f)
    A[f] = *(const v8s*)(GA + (size_t)(f * 64 + l) * 8);

  /* initial state: uniform; wave-0 chain WARM/CLEN starts exactly at u0 */
  v4f w[8];
#pragma unroll
  for (int m = 0; m < 8; ++m)
    w[m] = (v4f){1.0f / MST, 1.0f / MST, 1.0f / MST, 1.0f / MST};
  if (wid == 0 && c == (WARM / CLEN)) {
#pragma unroll
    for (int m = 0; m < 8; ++m)
      w[m] = *(const v4f*)(u0 + (m >> 1) * 32 + h * 8 + (m & 1) * 4);
  }
  float inv = 1.0f;

  v8s Bh[4];
  packBh(w, Bh);

  /* g pipeline: three raw bf16 row-buffers, refilled in place; buffer = n mod 3 */
  unsigned gvo = (unsigned)((t0 + GPAD) * 256 + h * 16);
  v4u gA[4], gB[4], gC[4];
#pragma unroll
  for (int mm = 0; mm < 4; ++mm) {
    gA[mm] = *(const v4u*)(gbase + (gvo + (unsigned)mm * 64u));
    gB[mm] = *(const v4u*)(gbase + (gvo + 256u + (unsigned)mm * 64u));
    gC[mm] = *(const v4u*)(gbase + (gvo + 512u + (unsigned)mm * 64u));
  }
  gvo += 768u;                                   /* -> t0+3 */
  unsigned uvo = (unsigned)(t0 * 512 + h * 32);

#define SARG wid, c, h, A, Bh
#define TAIL inv, gvo, uvo, gbase, u0, outUt, outF, outUtt
  /* 40 steps: 13 rolled triples + 1 tail; live when n >= 32 */
#pragma clang loop unroll(disable)
  for (int n = 0; n < 39; n += 3) {
    step(n + 0, SARG, gA, TAIL);
    step(n + 1, SARG, gB, TAIL);
    step(n + 2, SARG, gC, TAIL);
  }
  step(39, SARG, gA, TAIL);
#undef SARG
#undef TAIL
}

extern "C" void kernel_launch(void* const* d_in, const int* in_sizes, int n_in,
                              void* d_out, int out_size, void* d_ws, size_t ws_size,
                              hipStream_t stream) {
  const float* y  = (const float*)d_in[0];
  const float* tl = (const float*)d_in[1];
  const float* il = (const float*)d_in[2];
  const float* mu = (const float*)d_in[3];
  const float* ls = (const float*)d_in[4];

  /* ws: bf16 g (padded) | u0 | Gf | GA | isb | cstb  (~34 MB) */
  unsigned short* gf16 = (unsigned short*)d_ws;         /* (GPAD+TLEN+GPAD) x 128 bf16 */
  unsigned short* g0   = gf16 + (size_t)GPAD * MST;
  float* u0 = (float*)(gf16 + (size_t)(TLEN + 2 * GPAD) * MST);
  float* Gf = u0 + MST;
  unsigned short* GA = (unsigned short*)(Gf + MST * MST);
  float* isb  = (float*)(GA + 32 * 64 * 8);
  float* cstb = isb + MST * DOBS;

  char* outUt  = (char*)d_out;
  char* outF   = outUt + (size_t)TLEN * MST * 4;
  char* outUtt = outF + (size_t)TLEN * 4;

  build_params<<<MST + 1, MST, 0, stream>>>(tl, il, ls, Gf, u0, isb, cstb);
  build_afrag<<<32, 64, 0, stream>>>(Gf, GA);
  emis_kernel<<<TLEN / EROWS, MST, 0, stream>>>(y, mu, isb, cstb, g0);
  hmm_scan<<<NW, 64, 0, stream>>>((const char*)gf16, GA, u0, outUt, outF, outUtt);
}

// Round 14
// 68.565 us; speedup vs baseline: 1.7429x; 1.1433x over previous
//
#include <hip/hip_runtime.h>
#include <math.h>

#define MST   128
#define DOBS  8
#define TLEN  131072
#define LOG2PI_F 1.8378770664093453f

#define CLEN  8
#define NW    (TLEN / CLEN / 16)   /* 1024 waves: one per SIMD */
#define WARM  16
#define NSTEP (WARM + CLEN)        /* 24 */
#define GPAD  128
#define EROWS 16

typedef __attribute__((ext_vector_type(8))) short v8s;
typedef __attribute__((ext_vector_type(4))) float v4f;
typedef __attribute__((ext_vector_type(4))) unsigned int v4u;

__device__ __forceinline__ unsigned short f2bf_rne(float x) {
  unsigned int b = __builtin_bit_cast(unsigned int, x);
  unsigned int r = b + 0x7FFFu + ((b >> 16) & 1u);
  return (unsigned short)(r >> 16);
}
__device__ __forceinline__ unsigned cvtpk(float a, float b) {
  unsigned r;
  asm("v_cvt_pk_bf16_f32 %0, %1, %2" : "=v"(r) : "v"(a), "v"(b));
  return r;
}
__device__ __forceinline__ float bflo(unsigned u) {
  return __builtin_bit_cast(float, u << 16);
}
__device__ __forceinline__ float bfhi(unsigned u) {
  return __builtin_bit_cast(float, u & 0xFFFF0000u);
}

/* ---------- kernel 1: Gamma (f32, [src][dst]) + u0 + emission consts ---------- */
__global__ void build_params(const float* __restrict__ tl,
                             const float* __restrict__ il,
                             const float* __restrict__ ls,
                             float* __restrict__ Gf,
                             float* __restrict__ u0,
                             float* __restrict__ isb,
                             float* __restrict__ cstb) {
  __shared__ float red[MST];
  const int j = threadIdx.x;
  const int b = blockIdx.x;
  float lg;
  if (b < MST) lg = (j == b) ? 0.0f : tl[b * (MST - 1) + (j > b ? j - 1 : j)];
  else         lg = il[j];
  float e = __expf(lg);
  red[j] = e;
  __syncthreads();
  for (int s = MST / 2; s > 0; s >>= 1) {
    if (j < s) red[j] += red[j + s];
    __syncthreads();
  }
  float val = e / red[0];
  if (b < MST) {
    Gf[b * MST + j] = val;
  } else {
    u0[j] = val;
    float c = -((float)DOBS * 0.5f) * LOG2PI_F;
#pragma unroll
    for (int d = 0; d < DOBS; ++d) {
      float l = ls[j * DOBS + d];
      isb[j * DOBS + d] = __expf(-l);
      c -= l;
    }
    cstb[j] = c;
  }
}

/* ---------- kernel 1b: permuted Gamma^T A-fragments (bf16 RNE) ---------- */
__global__ void build_afrag(const float* __restrict__ Gf,
                            unsigned short* __restrict__ GA) {
  const int idx = blockIdx.x * 64 + threadIdx.x;  /* (m*4+kt)*64 + l */
  const int l  = idx & 63;
  const int mk = idx >> 6;
  const int kt = mk & 3, m = mk >> 2;
  const int i  = l & 15, hh = l >> 4;
  const int rg = 16 * m + i;
  const int lam = ((rg >> 5) << 5) | (((rg >> 2) & 3) << 3) | (((rg >> 4) & 1) << 2) | (rg & 3);
  unsigned short o[8];
#pragma unroll
  for (int j = 0; j < 8; ++j) {
    const int src = 32 * kt + 8 * hh + j;
    o[j] = f2bf_rne(Gf[src * MST + lam]);
  }
  *(v4u*)(GA + (size_t)idx * 8) = *(const v4u*)o;
}

/* ---------- kernel 2: emission densities -> bf16, XCD-aligned with consumer ---------- */
__global__ void emis_kernel(const float* __restrict__ y,
                            const float* __restrict__ mu,
                            const float* __restrict__ isb,
                            const float* __restrict__ cstb,
                            unsigned short* __restrict__ g0) {
  /* logical block: contiguous t-ranges stay on one XCD (matches scan swizzle) */
  const int lb = ((blockIdx.x & 7) << 10) | (blockIdx.x >> 3);
  const int j  = threadIdx.x;
  const int tb = lb * EROWS;
  __shared__ float ysh[EROWS * DOBS];
  ysh[j] = y[(unsigned)tb * DOBS + j];
  __syncthreads();
  float m[DOBS], is[DOBS];
  float cst = cstb[j];
#pragma unroll
  for (int d = 0; d < DOBS; ++d) { m[d] = mu[j * DOBS + d]; is[d] = isb[j * DOBS + d]; }
#pragma unroll
  for (int r = 0; r < EROWS; ++r) {
    float q = 0.0f;
#pragma unroll
    for (int d = 0; d < DOBS; ++d) {
      float z = (ysh[r * DOBS + d] - m[d]) * is[d];
      q = fmaf(z, z, q);
    }
    g0[(unsigned)(tb + r) * MST + j] = f2bf_rne(__expf(fmaf(-0.5f, q, cst)));
  }
}

/* ---------- scan internals ---------- */
__device__ __forceinline__ void packBh(const v4f* w, v8s* Bh) {
#pragma unroll
  for (int kt = 0; kt < 4; ++kt) {
    const v4f wa = w[2 * kt], wb = w[2 * kt + 1];
    Bh[kt] = __builtin_bit_cast(v8s, (v4u){cvtpk(wa[0], wa[1]), cvtpk(wa[2], wa[3]),
                                           cvtpk(wb[0], wb[1]), cvtpk(wb[2], wb[3])});
  }
}

/* one scan step: consumes `cur` (g[tcur] raw bf16), refills it with g[tcur+3].
   Hi-only state (bf16 RNE); live = n >= WARM (wave-uniform runtime branch). */
__device__ __forceinline__ void step(
    int n, int wid, int c, int h,
    const v8s* A, v8s* Bh, v4u (&cur)[4],
    float& inv, unsigned& gvo, unsigned& uvo,
    const char* gbase, const float* u0,
    char* outUt, char* outF, char* outUtt) {
  const bool live = n >= WARM;

  /* 1. D = W~ @ Gamma (hi-only state) */
  v4f D[8] = {};
#pragma unroll
  for (int kt = 0; kt < 4; ++kt)
#pragma unroll
    for (int m = 0; m < 8; ++m)
      D[m] = __builtin_amdgcn_mfma_f32_16x16x32_bf16(A[m * 4 + kt], Bh[kt], D[m], 0, 0, 0);

  /* 2. convert g (bf16->f32), fold inv_{n-1} */
  v4f gci[8];
#pragma unroll
  for (int mm = 0; mm < 4; ++mm) {
    const v4u raw = cur[mm];
    gci[2 * mm + 0] = (v4f){bflo(raw.x), bfhi(raw.x), bflo(raw.y), bfhi(raw.y)} * inv;
    gci[2 * mm + 1] = (v4f){bflo(raw.z), bfhi(raw.z), bflo(raw.w), bfhi(raw.w)} * inv;
  }

  /* 3. refill cur with g[tcur+3] (3-step latency slack; XCD-L2-local) */
#pragma unroll
  for (int mm = 0; mm < 4; ++mm)
    cur[mm] = *(const v4u*)(gbase + (gvo + (unsigned)mm * 64u));
  gvo += 256u;

  /* 4. predicted dist -> Utt (live); w~ = p~ * g */
  if (live) {
#pragma unroll
    for (int m = 0; m < 8; ++m) {
      v4f p = D[m] * inv;
      *(v4f*)(outUtt + (uvo + (m >> 1) * 128 + (m & 1) * 16)) = p;
    }
  }
  v4f w[8];
#pragma unroll
  for (int m = 0; m < 8; ++m) w[m] = D[m] * gci[m];

  /* 5. exact u0 injection for wave-0 early chains (state at t=-1 := u0) */
  if (wid == 0 && n < WARM && ((n & 7) == 7)) {
    const int ctar = (WARM - 1 - n) >> 3;
#pragma unroll
    for (int m = 0; m < 8; ++m) {
      v4f uv = *(const v4f*)(u0 + (m >> 1) * 32 + h * 8 + (m & 1) * 4);
      if (c == ctar) w[m] = uv;
    }
  }

  /* 6. rowsum S = f_t */
  v4f a0 = w[0] + w[1], a1 = w[2] + w[3], a2 = w[4] + w[5], a3 = w[6] + w[7];
  v4f a6 = (a0 + a1) + (a2 + a3);
  float s = (a6[0] + a6[1]) + (a6[2] + a6[3]);
  s += __shfl_xor(s, 16);
  s += __shfl_xor(s, 32);
  const float invn = __builtin_amdgcn_rcpf(s);

  /* 7. repack state (hi-only, layout-closed) */
  packBh(w, Bh);

  /* 8. filtered dist + f (live) */
  if (live) {
#pragma unroll
    for (int m = 0; m < 8; ++m) {
      v4f ut = w[m] * invn;
      *(v4f*)(outUt + (uvo + (m >> 1) * 128 + (m & 1) * 16)) = ut;
    }
    if (h == 0) *(float*)(outF + (uvo >> 7)) = s;
  }
  uvo += 512u;
  inv = invn;
}

/* ---------- kernel 3: barrier-free in-register MFMA scan, hi-only state ---------- */
__global__ __launch_bounds__(64, 1)
void hmm_scan(const char* __restrict__ gbase,     /* bf16 rows: g[t] at (t+GPAD)*256 B */
              const unsigned short* __restrict__ GA,
              const float* __restrict__ u0,
              char* __restrict__ outUt,
              char* __restrict__ outF,
              char* __restrict__ outUtt) {
  const int l = threadIdx.x;
  const int h = l >> 4, c = l & 15;
  /* XCD swizzle: waves sharing a g-region land on one XCD */
  const int wid = ((blockIdx.x & 7) << 7) | (blockIdx.x >> 3);
  const int t00 = (wid * 16 + c) * CLEN;
  const int t0  = t00 - WARM;

  /* Gamma^T A-fragments: 32 x v8s = 128 VGPR, loop-invariant */
  v8s A[32];
#pragma unroll
  for (int f = 0; f < 32; ++f)
    A[f] = *(const v8s*)(GA + (size_t)(f * 64 + l) * 8);

  /* initial state: uniform; wave-0 chain WARM/CLEN starts exactly at u0 */
  v4f w[8];
#pragma unroll
  for (int m = 0; m < 8; ++m)
    w[m] = (v4f){1.0f / MST, 1.0f / MST, 1.0f / MST, 1.0f / MST};
  if (wid == 0 && c == (WARM / CLEN)) {
#pragma unroll
    for (int m = 0; m < 8; ++m)
      w[m] = *(const v4f*)(u0 + (m >> 1) * 32 + h * 8 + (m & 1) * 4);
  }
  float inv = 1.0f;

  v8s Bh[4];
  packBh(w, Bh);

  /* g pipeline: three raw bf16 row-buffers, refilled in place; buffer = n mod 3 */
  unsigned gvo = (unsigned)((t0 + GPAD) * 256 + h * 16);
  v4u gA[4], gB[4], gC[4];
#pragma unroll
  for (int mm = 0; mm < 4; ++mm) {
    gA[mm] = *(const v4u*)(gbase + (gvo + (unsigned)mm * 64u));
    gB[mm] = *(const v4u*)(gbase + (gvo + 256u + (unsigned)mm * 64u));
    gC[mm] = *(const v4u*)(gbase + (gvo + 512u + (unsigned)mm * 64u));
  }
  gvo += 768u;                                   /* -> t0+3 */
  unsigned uvo = (unsigned)(t0 * 512 + h * 32);

#define SARG wid, c, h, A, Bh
#define TAIL inv, gvo, uvo, gbase, u0, outUt, outF, outUtt
  /* 24 steps: 8 rolled triples; live when n >= 16 */
#pragma clang loop unroll(disable)
  for (int n = 0; n < 24; n += 3) {
    step(n + 0, SARG, gA, TAIL);
    step(n + 1, SARG, gB, TAIL);
    step(n + 2, SARG, gC, TAIL);
  }
#undef SARG
#undef TAIL
}

extern "C" void kernel_launch(void* const* d_in, const int* in_sizes, int n_in,
                              void* d_out, int out_size, void* d_ws, size_t ws_size,
                              hipStream_t stream) {
  const float* y  = (const float*)d_in[0];
  const float* tl = (const float*)d_in[1];
  const float* il = (const float*)d_in[2];
  const float* mu = (const float*)d_in[3];
  const float* ls = (const float*)d_in[4];

  /* ws: bf16 g (padded) | u0 | Gf | GA | isb | cstb  (~34 MB) */
  unsigned short* gf16 = (unsigned short*)d_ws;         /* (GPAD+TLEN+GPAD) x 128 bf16 */
  unsigned short* g0   = gf16 + (size_t)GPAD * MST;
  float* u0 = (float*)(gf16 + (size_t)(TLEN + 2 * GPAD) * MST);
  float* Gf = u0 + MST;
  unsigned short* GA = (unsigned short*)(Gf + MST * MST);
  float* isb  = (float*)(GA + 32 * 64 * 8);
  float* cstb = isb + MST * DOBS;

  char* outUt  = (char*)d_out;
  char* outF   = outUt + (size_t)TLEN * MST * 4;
  char* outUtt = outF + (size_t)TLEN * 4;

  build_params<<<MST + 1, MST, 0, stream>>>(tl, il, ls, Gf, u0, isb, cstb);
  build_afrag<<<32, 64, 0, stream>>>(Gf, GA);
  emis_kernel<<<TLEN / EROWS, MST, 0, stream>>>(y, mu, isb, cstb, g0);
  hmm_scan<<<NW, 64, 0, stream>>>((const char*)gf16, GA, u0, outUt, outF, outUtt);
}

// Round 15
// 67.988 us; speedup vs baseline: 1.7577x; 1.0085x over previous
//
#include <hip/hip_runtime.h>
#include <math.h>

#define MST   128
#define DOBS  8
#define TLEN  131072
#define LOG2PI_F 1.8378770664093453f

#define CLEN  8
#define NW    (TLEN / CLEN / 16)   /* 1024 waves: one per SIMD */
#define WARM  16
#define NSTEP (WARM + CLEN)        /* 24 */
#define GPAD  128
#define EROWS 16

typedef __attribute__((ext_vector_type(8))) short v8s;
typedef __attribute__((ext_vector_type(4))) float v4f;
typedef __attribute__((ext_vector_type(4))) unsigned int v4u;

__device__ __forceinline__ unsigned short f2bf_rne(float x) {
  unsigned int b = __builtin_bit_cast(unsigned int, x);
  unsigned int r = b + 0x7FFFu + ((b >> 16) & 1u);
  return (unsigned short)(r >> 16);
}
__device__ __forceinline__ unsigned cvtpk(float a, float b) {
  unsigned r;
  asm("v_cvt_pk_bf16_f32 %0, %1, %2" : "=v"(r) : "v"(a), "v"(b));
  return r;
}
__device__ __forceinline__ float bflo(unsigned u) {
  return __builtin_bit_cast(float, u << 16);
}
__device__ __forceinline__ float bfhi(unsigned u) {
  return __builtin_bit_cast(float, u & 0xFFFF0000u);
}

/* ---------- kernel 1: Gamma (f32, [src][dst]) + u0 + emission consts ---------- */
__global__ void build_params(const float* __restrict__ tl,
                             const float* __restrict__ il,
                             const float* __restrict__ ls,
                             float* __restrict__ Gf,
                             float* __restrict__ u0,
                             float* __restrict__ isb,
                             float* __restrict__ cstb) {
  __shared__ float red[MST];
  const int j = threadIdx.x;
  const int b = blockIdx.x;
  float lg;
  if (b < MST) lg = (j == b) ? 0.0f : tl[b * (MST - 1) + (j > b ? j - 1 : j)];
  else         lg = il[j];
  float e = __expf(lg);
  red[j] = e;
  __syncthreads();
  for (int s = MST / 2; s > 0; s >>= 1) {
    if (j < s) red[j] += red[j + s];
    __syncthreads();
  }
  float val = e / red[0];
  if (b < MST) {
    Gf[b * MST + j] = val;
  } else {
    u0[j] = val;
    float c = -((float)DOBS * 0.5f) * LOG2PI_F;
#pragma unroll
    for (int d = 0; d < DOBS; ++d) {
      float l = ls[j * DOBS + d];
      isb[j * DOBS + d] = __expf(-l);
      c -= l;
    }
    cstb[j] = c;
  }
}

/* ---------- kernel 1b: permuted Gamma^T A-fragments (bf16 RNE) ---------- */
__global__ void build_afrag(const float* __restrict__ Gf,
                            unsigned short* __restrict__ GA) {
  const int idx = blockIdx.x * 64 + threadIdx.x;  /* (m*4+kt)*64 + l */
  const int l  = idx & 63;
  const int mk = idx >> 6;
  const int kt = mk & 3, m = mk >> 2;
  const int i  = l & 15, hh = l >> 4;
  const int rg = 16 * m + i;
  const int lam = ((rg >> 5) << 5) | (((rg >> 2) & 3) << 3) | (((rg >> 4) & 1) << 2) | (rg & 3);
  unsigned short o[8];
#pragma unroll
  for (int j = 0; j < 8; ++j) {
    const int src = 32 * kt + 8 * hh + j;
    o[j] = f2bf_rne(Gf[src * MST + lam]);
  }
  *(v4u*)(GA + (size_t)idx * 8) = *(const v4u*)o;
}

/* ---------- kernel 2: emission densities -> bf16, XCD-aligned with consumer ---------- */
__global__ void emis_kernel(const float* __restrict__ y,
                            const float* __restrict__ mu,
                            const float* __restrict__ isb,
                            const float* __restrict__ cstb,
                            unsigned short* __restrict__ g0) {
  /* logical block: contiguous t-ranges stay on one XCD (matches scan swizzle) */
  const int lb = ((blockIdx.x & 7) << 10) | (blockIdx.x >> 3);
  const int j  = threadIdx.x;
  const int tb = lb * EROWS;
  __shared__ float ysh[EROWS * DOBS];
  ysh[j] = y[(unsigned)tb * DOBS + j];
  __syncthreads();
  float m[DOBS], is[DOBS];
  float cst = cstb[j];
#pragma unroll
  for (int d = 0; d < DOBS; ++d) { m[d] = mu[j * DOBS + d]; is[d] = isb[j * DOBS + d]; }
#pragma unroll
  for (int r = 0; r < EROWS; ++r) {
    float q = 0.0f;
#pragma unroll
    for (int d = 0; d < DOBS; ++d) {
      float z = (ysh[r * DOBS + d] - m[d]) * is[d];
      q = fmaf(z, z, q);
    }
    g0[(unsigned)(tb + r) * MST + j] = f2bf_rne(__expf(fmaf(-0.5f, q, cst)));
  }
}

/* ---------- scan internals ---------- */
__device__ __forceinline__ void packBh(const v4f* w, v8s* Bh) {
#pragma unroll
  for (int kt = 0; kt < 4; ++kt) {
    const v4f wa = w[2 * kt], wb = w[2 * kt + 1];
    Bh[kt] = __builtin_bit_cast(v8s, (v4u){cvtpk(wa[0], wa[1]), cvtpk(wa[2], wa[3]),
                                           cvtpk(wb[0], wb[1]), cvtpk(wb[2], wb[3])});
  }
}

/* one scan step. Outputs staged in LDS (XOR-swizzled), then stored coalesced:
   each global-store instruction covers two complete 512B rows. */
__device__ __forceinline__ void step(
    int n, int wid, int c, int h, int j32, int cg,
    const v8s* A, v8s* Bh, v4u (&cur)[4],
    float& inv, unsigned& gvo,
    const char* gbase, const float* u0,
    char* LUt, char* LUtt,
    char* outUt, char* outF, char* outUtt,
    unsigned sbase, unsigned foff) {
  const bool live = n >= WARM;

  /* 1. D = W~ @ Gamma (hi-only state) */
  v4f D[8] = {};
#pragma unroll
  for (int kt = 0; kt < 4; ++kt)
#pragma unroll
    for (int m = 0; m < 8; ++m)
      D[m] = __builtin_amdgcn_mfma_f32_16x16x32_bf16(A[m * 4 + kt], Bh[kt], D[m], 0, 0, 0);

  /* 2. convert g (bf16->f32), fold inv_{n-1} */
  v4f gci[8];
#pragma unroll
  for (int mm = 0; mm < 4; ++mm) {
    const v4u raw = cur[mm];
    gci[2 * mm + 0] = (v4f){bflo(raw.x), bfhi(raw.x), bflo(raw.y), bfhi(raw.y)} * inv;
    gci[2 * mm + 1] = (v4f){bflo(raw.z), bfhi(raw.z), bflo(raw.w), bfhi(raw.w)} * inv;
  }

  /* 3. refill cur with g[tcur+3] (3-step latency slack; XCD-L2-local) */
#pragma unroll
  for (int mm = 0; mm < 4; ++mm)
    cur[mm] = *(const v4u*)(gbase + (gvo + (unsigned)mm * 64u));
  gvo += 256u;

  /* 4. stage predicted dist (Utt) in LDS; w~ = p~ * g */
  if (live) {
#pragma unroll
    for (int m = 0; m < 8; ++m) {
      v4f p = D[m] * inv;
      const int s = ((m >> 1) << 3) | (h << 1) | (m & 1);
      *(v4f*)(LUtt + (c << 9) + ((s ^ c) << 4)) = p;
    }
  }
  v4f w[8];
#pragma unroll
  for (int m = 0; m < 8; ++m) w[m] = D[m] * gci[m];

  /* 5. exact u0 injection for wave-0 early chains (state at t=-1 := u0) */
  if (wid == 0 && n < WARM && ((n & 7) == 7)) {
    const int ctar = (WARM - 1 - n) >> 3;
#pragma unroll
    for (int m = 0; m < 8; ++m) {
      v4f uv = *(const v4f*)(u0 + (m >> 1) * 32 + h * 8 + (m & 1) * 4);
      if (c == ctar) w[m] = uv;
    }
  }

  /* 6. rowsum S = f_t */
  v4f a0 = w[0] + w[1], a1 = w[2] + w[3], a2 = w[4] + w[5], a3 = w[6] + w[7];
  v4f a6 = (a0 + a1) + (a2 + a3);
  float s = (a6[0] + a6[1]) + (a6[2] + a6[3]);
  s += __shfl_xor(s, 16);
  s += __shfl_xor(s, 32);
  const float invn = __builtin_amdgcn_rcpf(s);

  /* 7. repack state (hi-only, layout-closed) */
  packBh(w, Bh);

  /* 8. stage Ut, store f, then coalesced read-back + global store */
  if (live) {
#pragma unroll
    for (int m = 0; m < 8; ++m) {
      v4f ut = w[m] * invn;
      const int sl = ((m >> 1) << 3) | (h << 1) | (m & 1);
      *(v4f*)(LUt + (c << 9) + ((sl ^ c) << 4)) = ut;
    }
    const unsigned d = (unsigned)(n - WARM);
    if (h == 0) *(float*)(outF + foff + d * 4u) = s;
    unsigned off = sbase + d * 512u;
#pragma unroll
    for (int i = 0; i < 8; ++i) {
      const int ci = 2 * i + cg;
      const unsigned lo = (unsigned)(ci << 9) + (unsigned)((j32 ^ ci) << 4);
      v4f pa = *(const v4f*)(LUtt + lo);
      v4f ua = *(const v4f*)(LUt + lo);
      *(v4f*)(outUtt + off) = pa;
      *(v4f*)(outUt + off) = ua;
      off += 8192u;   /* 2 chains * CLEN * 512 */
    }
  }
  inv = invn;
}

/* ---------- kernel 3: barrier-free in-register MFMA scan, LDS-coalesced stores ---------- */
__global__ __launch_bounds__(64, 1)
void hmm_scan(const char* __restrict__ gbase,     /* bf16 rows: g[t] at (t+GPAD)*256 B */
              const unsigned short* __restrict__ GA,
              const float* __restrict__ u0,
              char* __restrict__ outUt,
              char* __restrict__ outF,
              char* __restrict__ outUtt) {
  __shared__ __align__(16) char LUt[16 * 512];
  __shared__ __align__(16) char LUtt[16 * 512];

  const int l = threadIdx.x;
  const int h = l >> 4, c = l & 15;
  const int j32 = l & 31, cg = l >> 5;
  /* XCD swizzle: waves sharing a g-region land on one XCD */
  const int wid = ((blockIdx.x & 7) << 7) | (blockIdx.x >> 3);
  const int t00 = (wid * 16 + c) * CLEN;
  const int t0  = t00 - WARM;

  /* lane constants for coalesced store path */
  const unsigned sbase = (unsigned)(wid * 16 + cg) * 4096u + (unsigned)j32 * 16u;
  const unsigned foff  = (unsigned)((wid * 16 + c) * CLEN) * 4u;

  /* Gamma^T A-fragments: 32 x v8s = 128 VGPR, loop-invariant */
  v8s A[32];
#pragma unroll
  for (int f = 0; f < 32; ++f)
    A[f] = *(const v8s*)(GA + (size_t)(f * 64 + l) * 8);

  /* initial state: uniform; wave-0 chain WARM/CLEN starts exactly at u0 */
  v4f w[8];
#pragma unroll
  for (int m = 0; m < 8; ++m)
    w[m] = (v4f){1.0f / MST, 1.0f / MST, 1.0f / MST, 1.0f / MST};
  if (wid == 0 && c == (WARM / CLEN)) {
#pragma unroll
    for (int m = 0; m < 8; ++m)
      w[m] = *(const v4f*)(u0 + (m >> 1) * 32 + h * 8 + (m & 1) * 4);
  }
  float inv = 1.0f;

  v8s Bh[4];
  packBh(w, Bh);

  /* g pipeline: three raw bf16 row-buffers, refilled in place; buffer = n mod 3 */
  unsigned gvo = (unsigned)((t0 + GPAD) * 256 + h * 16);
  v4u gA[4], gB[4], gC[4];
#pragma unroll
  for (int mm = 0; mm < 4; ++mm) {
    gA[mm] = *(const v4u*)(gbase + (gvo + (unsigned)mm * 64u));
    gB[mm] = *(const v4u*)(gbase + (gvo + 256u + (unsigned)mm * 64u));
    gC[mm] = *(const v4u*)(gbase + (gvo + 512u + (unsigned)mm * 64u));
  }
  gvo += 768u;                                   /* -> t0+3 */

#define SARG wid, c, h, j32, cg, A, Bh
#define TAIL inv, gvo, gbase, u0, LUt, LUtt, outUt, outF, outUtt, sbase, foff
  /* 24 steps: 8 rolled triples; live when n >= 16 */
#pragma clang loop unroll(disable)
  for (int n = 0; n < 24; n += 3) {
    step(n + 0, SARG, gA, TAIL);
    step(n + 1, SARG, gB, TAIL);
    step(n + 2, SARG, gC, TAIL);
  }
#undef SARG
#undef TAIL
}

extern "C" void kernel_launch(void* const* d_in, const int* in_sizes, int n_in,
                              void* d_out, int out_size, void* d_ws, size_t ws_size,
                              hipStream_t stream) {
  const float* y  = (const float*)d_in[0];
  const float* tl = (const float*)d_in[1];
  const float* il = (const float*)d_in[2];
  const float* mu = (const float*)d_in[3];
  const float* ls = (const float*)d_in[4];

  /* ws: bf16 g (padded) | u0 | Gf | GA | isb | cstb  (~34 MB) */
  unsigned short* gf16 = (unsigned short*)d_ws;         /* (GPAD+TLEN+GPAD) x 128 bf16 */
  unsigned short* g0   = gf16 + (size_t)GPAD * MST;
  float* u0 = (float*)(gf16 + (size_t)(TLEN + 2 * GPAD) * MST);
  float* Gf = u0 + MST;
  unsigned short* GA = (unsigned short*)(Gf + MST * MST);
  float* isb  = (float*)(GA + 32 * 64 * 8);
  float* cstb = isb + MST * DOBS;

  char* outUt  = (char*)d_out;
  char* outF   = outUt + (size_t)TLEN * MST * 4;
  char* outUtt = outF + (size_t)TLEN * 4;

  build_params<<<MST + 1, MST, 0, stream>>>(tl, il, ls, Gf, u0, isb, cstb);
  build_afrag<<<32, 64, 0, stream>>>(Gf, GA);
  emis_kernel<<<TLEN / EROWS, MST, 0, stream>>>(y, mu, isb, cstb, g0);
  hmm_scan<<<NW, 64, 0, stream>>>((const char*)gf16, GA, u0, outUt, outF, outUtt);
}